// Round 1
// baseline (233.781 us; speedup 1.0000x reference)
//
#include <hip/hip_runtime.h>
#include <hip/hip_bf16.h>
#include <math.h>

#define B 4
#define N 256
#define DIN 4
#define D 64
#define NH 4
#define NL 2
#define DH 16

constexpr float EPS = 1e-5f;
constexpr float SLOPE = 0.01f;

// ---------------------------------------------------------------------------
// Phase B: rowsum[n, b, i] = sum_j exp(leaky(feature[b,i,j,:]·M[n] + c[n]))
// where M[n][k] = sum_d W1[k][d]*mw[n][d], c[n] = b1·mw[n] + mb[n].
// grid = B*N (one block per (b,i)), block = 256 (one thread per j)
// ---------------------------------------------------------------------------
__global__ void k_rowsum(const float* __restrict__ feature,
                         const float* __restrict__ W1,
                         const float* __restrict__ b1,
                         const float* __restrict__ mw,
                         const float* __restrict__ mb,
                         float* __restrict__ rs) {
    __shared__ float M[NH][DIN];
    __shared__ float C[NH];
    __shared__ float part[4][NH];
    int t = threadIdx.x;
    if (t < NH * DIN) {
        int n = t / DIN, kk = t % DIN;
        float s = 0.f;
        for (int d = 0; d < D; ++d) s += W1[kk * D + d] * mw[n * D + d];
        M[n][kk] = s;
    } else if (t < NH * DIN + NH) {
        int n = t - NH * DIN;
        float s = mb[n];
        for (int d = 0; d < D; ++d) s += b1[d] * mw[n * D + d];
        C[n] = s;
    }
    __syncthreads();

    int bi = blockIdx.x;  // b*N + i
    const float4 f = *(const float4*)(feature + ((size_t)bi * N + t) * DIN);
    float e[NH];
#pragma unroll
    for (int n = 0; n < NH; ++n) {
        float s = C[n] + f.x * M[n][0] + f.y * M[n][1] + f.z * M[n][2] + f.w * M[n][3];
        s = (s >= 0.f) ? s : SLOPE * s;
        e[n] = __expf(s);
    }
    int lane = t & 63, wv = t >> 6;
#pragma unroll
    for (int n = 0; n < NH; ++n) {
        float v = e[n];
        for (int off = 32; off > 0; off >>= 1) v += __shfl_down(v, off);
        if (lane == 0) part[wv][n] = v;
    }
    __syncthreads();
    if (t < NH) rs[bi * NH + t] = part[0][t] + part[1][t] + part[2][t] + part[3][t];
}

// ---------------------------------------------------------------------------
// Phase C: g[b,j,0:4] = sum_i wbar * feature[b,i,j,:], S = sum_i wbar,
// then h[b,j,:] = g·W1 + S*b1.  grid = B*N (one block per (b,j)), block = 256.
// ---------------------------------------------------------------------------
__global__ void k_aggregate(const float* __restrict__ feature,
                            const float* __restrict__ W1,
                            const float* __restrict__ b1,
                            const float* __restrict__ mw,
                            const float* __restrict__ mb,
                            const float* __restrict__ rs,
                            float* __restrict__ h) {
    __shared__ float M[NH][DIN];
    __shared__ float C[NH];
    __shared__ float part[4][5];
    __shared__ float gacc[5];
    int t = threadIdx.x;
    if (t < NH * DIN) {
        int n = t / DIN, kk = t % DIN;
        float s = 0.f;
        for (int d = 0; d < D; ++d) s += W1[kk * D + d] * mw[n * D + d];
        M[n][kk] = s;
    } else if (t < NH * DIN + NH) {
        int n = t - NH * DIN;
        float s = mb[n];
        for (int d = 0; d < D; ++d) s += b1[d] * mw[n * D + d];
        C[n] = s;
    }
    __syncthreads();

    int blk = blockIdx.x;        // b*N + j
    int b = blk >> 8;            // / N
    int j = blk & (N - 1);
    int i = t;
    const float4 f = *(const float4*)(feature + (((size_t)(b * N + i)) * N + j) * DIN);
    const float4 r4 = *(const float4*)(rs + (size_t)(b * N + i) * NH);
    float wbar = 0.f;
    {
        float rsv[NH] = {r4.x, r4.y, r4.z, r4.w};
#pragma unroll
        for (int n = 0; n < NH; ++n) {
            float s = C[n] + f.x * M[n][0] + f.y * M[n][1] + f.z * M[n][2] + f.w * M[n][3];
            s = (s >= 0.f) ? s : SLOPE * s;
            wbar += __expf(s) / rsv[n];
        }
    }
    wbar *= (1.0f / NH);
    float acc[5] = {wbar * f.x, wbar * f.y, wbar * f.z, wbar * f.w, wbar};

    int lane = t & 63, wv = t >> 6;
#pragma unroll
    for (int n = 0; n < 5; ++n) {
        float v = acc[n];
        for (int off = 32; off > 0; off >>= 1) v += __shfl_down(v, off);
        if (lane == 0) part[wv][n] = v;
    }
    __syncthreads();
    if (t < 5) gacc[t] = part[0][t] + part[1][t] + part[2][t] + part[3][t];
    __syncthreads();
    if (t < D) {
        float hv = gacc[4] * b1[t];
#pragma unroll
        for (int kk = 0; kk < DIN; ++kk) hv += gacc[kk] * W1[kk * D + t];
        h[(size_t)blk * D + t] = hv;
    }
}

// ---------------------------------------------------------------------------
// BatchNorm stats over (B,N) per channel. grid = D, block = 256.
// ---------------------------------------------------------------------------
__global__ void k_bnstats(const float* __restrict__ h,
                          float* __restrict__ mean, float* __restrict__ inv) {
    __shared__ float ps[4], pq[4];
    int d = blockIdx.x, t = threadIdx.x;
    float s = 0.f, sq = 0.f;
    for (int r = t; r < B * N; r += 256) {
        float v = h[(size_t)r * D + d];
        s += v;
        sq += v * v;
    }
    int lane = t & 63, wv = t >> 6;
    for (int off = 32; off > 0; off >>= 1) {
        s += __shfl_down(s, off);
        sq += __shfl_down(sq, off);
    }
    if (lane == 0) { ps[wv] = s; pq[wv] = sq; }
    __syncthreads();
    if (t == 0) {
        float S = ps[0] + ps[1] + ps[2] + ps[3];
        float Q = pq[0] + pq[1] + pq[2] + pq[3];
        float m = S * (1.0f / (B * N));
        float var = Q * (1.0f / (B * N)) - m * m;
        mean[d] = m;
        inv[d] = rsqrtf(var + EPS);
    }
}

// elementwise BN apply: x = gamma*(h-mean)*inv + beta. 65536 elements.
__global__ void k_bnapply(const float* __restrict__ h,
                          const float* __restrict__ mean, const float* __restrict__ inv,
                          const float* __restrict__ g, const float* __restrict__ be,
                          float* __restrict__ x) {
    int idx = blockIdx.x * 256 + threadIdx.x;
    int d = idx & (D - 1);
    x[idx] = g[d] * (h[idx] - mean[d]) * inv[d] + be[d];
}

// ---------------------------------------------------------------------------
// QKV projection. grid = B*N/4 (4 tokens/block), block = 256 (4 rows x 64 cols).
// Outputs laid out [b][head][n][dh] for attention locality.
// ---------------------------------------------------------------------------
__global__ void k_qkv(const float* __restrict__ x,
                      const float* __restrict__ Wq, const float* __restrict__ bq,
                      const float* __restrict__ Wk, const float* __restrict__ bk,
                      const float* __restrict__ Wv, const float* __restrict__ bv,
                      float* __restrict__ q, float* __restrict__ k, float* __restrict__ v) {
    __shared__ float xs[4][D];
    int t = threadIdx.x;
    int row0 = blockIdx.x * 4;
    xs[t >> 6][t & 63] = x[(size_t)row0 * D + t];
    __syncthreads();
    int r = t >> 6, cc = t & 63;
    int token = row0 + r;
    int b = token >> 8;          // / N
    int n = token & (N - 1);
    int head = cc >> 4, dh = cc & (DH - 1);
    size_t oidx = (((size_t)(b * NH + head)) * N + n) * DH + dh;
    float aq = bq[cc], ak = bk[cc], av = bv[cc];
#pragma unroll 8
    for (int kk = 0; kk < D; ++kk) {
        float xv = xs[r][kk];
        aq += xv * Wq[kk * D + cc];
        ak += xv * Wk[kk * D + cc];
        av += xv * Wv[kk * D + cc];
    }
    q[oidx] = aq; k[oidx] = ak; v[oidx] = av;
}

// ---------------------------------------------------------------------------
// Attention, online softmax. grid = (B*NH, N/64), block = 64 (one query/thread).
// K,V tiles for the (b,head) in LDS (32 KB).
// att output layout: [b][n][head*DH+dh] (token-major, D contiguous).
// ---------------------------------------------------------------------------
__global__ void k_attn(const float* __restrict__ q, const float* __restrict__ k,
                       const float* __restrict__ v, float* __restrict__ att) {
    __shared__ float Ks[N][DH];
    __shared__ float Vs[N][DH];
    int t = threadIdx.x;
    int bh = blockIdx.x;  // b*NH + head
    const float4* kbase = (const float4*)(k + (size_t)bh * N * DH);
    const float4* vbase = (const float4*)(v + (size_t)bh * N * DH);
#pragma unroll
    for (int it = 0; it < 16; ++it) {
        int idx = it * 64 + t;
        ((float4*)Ks)[idx] = kbase[idx];
        ((float4*)Vs)[idx] = vbase[idx];
    }
    __syncthreads();
    int qi = blockIdx.y * 64 + t;
    const float* qbase = q + ((size_t)bh * N + qi) * DH;
    float qr[DH];
#pragma unroll
    for (int d2 = 0; d2 < DH; ++d2) qr[d2] = qbase[d2] * 0.25f;  // 1/sqrt(16)
    float m = -1e30f, l = 0.f, o[DH];
#pragma unroll
    for (int d2 = 0; d2 < DH; ++d2) o[d2] = 0.f;
    for (int kk = 0; kk < N; ++kk) {
        float s = 0.f;
#pragma unroll
        for (int d2 = 0; d2 < DH; ++d2) s += qr[d2] * Ks[kk][d2];
        float mn = fmaxf(m, s);
        float corr = __expf(m - mn);
        float p = __expf(s - mn);
        l = l * corr + p;
#pragma unroll
        for (int d2 = 0; d2 < DH; ++d2) o[d2] = o[d2] * corr + p * Vs[kk][d2];
        m = mn;
    }
    float rl = 1.f / l;
    int b = bh >> 2, head = bh & (NH - 1);
    float* obase = att + ((size_t)(b * N + qi)) * D + head * DH;
#pragma unroll
    for (int d2 = 0; d2 < DH; ++d2) obase[d2] = o[d2] * rl;
}

// ---------------------------------------------------------------------------
// O-projection + residual + LayerNorm. grid = B*N (one token/block), block = 64.
// ---------------------------------------------------------------------------
__global__ void k_oproj_ln(const float* __restrict__ att, const float* __restrict__ Wo,
                           const float* __restrict__ bo, const float* __restrict__ lg,
                           const float* __restrict__ lb, float* __restrict__ x) {
    __shared__ float as[D];
    int t = threadIdx.x;
    int token = blockIdx.x;
    as[t] = att[(size_t)token * D + t];
    __syncthreads();
    float o = bo[t];
#pragma unroll 8
    for (int kk = 0; kk < D; ++kk) o += as[kk] * Wo[kk * D + t];
    float r = x[(size_t)token * D + t] + o;
    float s = r, sq = r * r;
    for (int off = 32; off > 0; off >>= 1) {
        s += __shfl_xor(s, off);
        sq += __shfl_xor(sq, off);
    }
    float mean = s * (1.0f / D);
    float var = sq * (1.0f / D) - mean * mean;
    float inv = rsqrtf(var + EPS);
    x[(size_t)token * D + t] = lg[t] * (r - mean) * inv + lb[t];
}

// ---------------------------------------------------------------------------
// FFN (64 -> 128 relu -> 64) + residual + LayerNorm. grid = B*N, block = 128.
// ---------------------------------------------------------------------------
__global__ void k_ffn_ln(const float* __restrict__ Wff1, const float* __restrict__ bff1,
                         const float* __restrict__ Wff2, const float* __restrict__ bff2,
                         const float* __restrict__ lg, const float* __restrict__ lb,
                         float* __restrict__ x) {
    __shared__ float xr[D];
    __shared__ float f1[2 * D];
    int t = threadIdx.x;
    int token = blockIdx.x;
    if (t < D) xr[t] = x[(size_t)token * D + t];
    __syncthreads();
    float a = bff1[t];
#pragma unroll 8
    for (int kk = 0; kk < D; ++kk) a += xr[kk] * Wff1[kk * 2 * D + t];
    f1[t] = fmaxf(a, 0.f);
    __syncthreads();
    if (t < D) {
        float o = bff2[t];
#pragma unroll 8
        for (int kk = 0; kk < 2 * D; ++kk) o += f1[kk] * Wff2[kk * D + t];
        float r = xr[t] + o;
        float s = r, sq = r * r;
        for (int off = 32; off > 0; off >>= 1) {
            s += __shfl_xor(s, off);
            sq += __shfl_xor(sq, off);
        }
        float mean = s * (1.0f / D);
        float var = sq * (1.0f / D) - mean * mean;
        float inv = rsqrtf(var + EPS);
        x[(size_t)token * D + t] = lg[t] * (r - mean) * inv + lb[t];
    }
}

extern "C" void kernel_launch(void* const* d_in, const int* in_sizes, int n_in,
                              void* d_out, int out_size, void* d_ws, size_t ws_size,
                              hipStream_t stream) {
    const float* feature = (const float*)d_in[0];
    const float* W1   = (const float*)d_in[1];
    const float* b1   = (const float*)d_in[2];
    const float* mw   = (const float*)d_in[3];
    const float* mb   = (const float*)d_in[4];
    const float* bn_g = (const float*)d_in[5];
    const float* bn_b = (const float*)d_in[6];
    const float* Wq   = (const float*)d_in[7];
    const float* bq   = (const float*)d_in[8];
    const float* Wk   = (const float*)d_in[9];
    const float* bk   = (const float*)d_in[10];
    const float* Wv   = (const float*)d_in[11];
    const float* bv   = (const float*)d_in[12];
    const float* Wo   = (const float*)d_in[13];
    const float* bo   = (const float*)d_in[14];
    const float* ln1g = (const float*)d_in[15];
    const float* ln1b = (const float*)d_in[16];
    const float* Wff1 = (const float*)d_in[17];
    const float* bff1 = (const float*)d_in[18];
    const float* Wff2 = (const float*)d_in[19];
    const float* bff2 = (const float*)d_in[20];
    const float* ln2g = (const float*)d_in[21];
    const float* ln2b = (const float*)d_in[22];

    float* ws   = (float*)d_ws;
    float* rs   = ws;                    // B*N*NH          = 4096
    float* h    = rs + B * N * NH;       // B*N*D           = 65536
    float* mean = h + B * N * D;         // D
    float* inv  = mean + D;              // D
    float* q    = inv + D;               // B*N*D
    float* k    = q + B * N * D;         // B*N*D
    float* v    = k + B * N * D;         // B*N*D
    float* att  = v + B * N * D;         // B*N*D
    float* x    = (float*)d_out;         // running (B,N,D) activation

    k_rowsum<<<B * N, 256, 0, stream>>>(feature, W1, b1, mw, mb, rs);
    k_aggregate<<<B * N, 256, 0, stream>>>(feature, W1, b1, mw, mb, rs, h);
    k_bnstats<<<D, 256, 0, stream>>>(h, mean, inv);
    k_bnapply<<<(B * N * D) / 256, 256, 0, stream>>>(h, mean, inv, bn_g, bn_b, x);

    for (int l = 0; l < NL; ++l) {
        k_qkv<<<(B * N) / 4, 256, 0, stream>>>(x,
            Wq + (size_t)l * D * D, bq + (size_t)l * D,
            Wk + (size_t)l * D * D, bk + (size_t)l * D,
            Wv + (size_t)l * D * D, bv + (size_t)l * D, q, k, v);
        dim3 g2(B * NH, N / 64);
        k_attn<<<g2, 64, 0, stream>>>(q, k, v, att);
        k_oproj_ln<<<B * N, 64, 0, stream>>>(att,
            Wo + (size_t)l * D * D, bo + (size_t)l * D,
            ln1g + (size_t)l * D, ln1b + (size_t)l * D, x);
        k_ffn_ln<<<B * N, 128, 0, stream>>>(
            Wff1 + (size_t)l * 2 * D * D, bff1 + (size_t)l * 2 * D,
            Wff2 + (size_t)l * 2 * D * D, bff2 + (size_t)l * D,
            ln2g + (size_t)l * D, ln2b + (size_t)l * D, x);
    }
}

// Round 2
// 173.787 us; speedup vs baseline: 1.3452x; 1.3452x over previous
//
#include <hip/hip_runtime.h>
#include <hip/hip_bf16.h>
#include <math.h>

#define B 4
#define N 256
#define DIN 4
#define D 64
#define NH 4
#define NL 2
#define DH 16

constexpr float EPS = 1e-5f;
constexpr float SLOPE = 0.01f;

// ---------------------------------------------------------------------------
// Phase B: rowsum[n, b, i] = sum_j exp(leaky(feature[b,i,j,:]·M[n] + c[n]))
// where M[n][k] = sum_d W1[k][d]*mw[n][d], c[n] = b1·mw[n] + mb[n].
// grid = B*N (one block per (b,i)), block = 256 (one thread per j)
// ---------------------------------------------------------------------------
__global__ void k_rowsum(const float* __restrict__ feature,
                         const float* __restrict__ W1,
                         const float* __restrict__ b1,
                         const float* __restrict__ mw,
                         const float* __restrict__ mb,
                         float* __restrict__ rs) {
    __shared__ float M[NH][DIN];
    __shared__ float C[NH];
    __shared__ float part[4][NH];
    int t = threadIdx.x;
    if (t < NH * DIN) {
        int n = t / DIN, kk = t % DIN;
        float s = 0.f;
        for (int d = 0; d < D; ++d) s += W1[kk * D + d] * mw[n * D + d];
        M[n][kk] = s;
    } else if (t < NH * DIN + NH) {
        int n = t - NH * DIN;
        float s = mb[n];
        for (int d = 0; d < D; ++d) s += b1[d] * mw[n * D + d];
        C[n] = s;
    }
    __syncthreads();

    int bi = blockIdx.x;  // b*N + i
    const float4 f = *(const float4*)(feature + ((size_t)bi * N + t) * DIN);
    float e[NH];
#pragma unroll
    for (int n = 0; n < NH; ++n) {
        float s = C[n] + f.x * M[n][0] + f.y * M[n][1] + f.z * M[n][2] + f.w * M[n][3];
        s = (s >= 0.f) ? s : SLOPE * s;
        e[n] = __expf(s);
    }
    int lane = t & 63, wv = t >> 6;
#pragma unroll
    for (int n = 0; n < NH; ++n) {
        float v = e[n];
        for (int off = 32; off > 0; off >>= 1) v += __shfl_down(v, off);
        if (lane == 0) part[wv][n] = v;
    }
    __syncthreads();
    if (t < NH) rs[bi * NH + t] = part[0][t] + part[1][t] + part[2][t] + part[3][t];
}

// ---------------------------------------------------------------------------
// Phase C: g[b,j,0:4] = sum_i wbar * feature[b,i,j,:], S = sum_i wbar,
// then h[b,j,:] = g·W1 + S*b1.  grid = B*N (one block per (b,j)), block = 256.
// ---------------------------------------------------------------------------
__global__ void k_aggregate(const float* __restrict__ feature,
                            const float* __restrict__ W1,
                            const float* __restrict__ b1,
                            const float* __restrict__ mw,
                            const float* __restrict__ mb,
                            const float* __restrict__ rs,
                            float* __restrict__ h) {
    __shared__ float M[NH][DIN];
    __shared__ float C[NH];
    __shared__ float part[4][5];
    __shared__ float gacc[5];
    int t = threadIdx.x;
    if (t < NH * DIN) {
        int n = t / DIN, kk = t % DIN;
        float s = 0.f;
        for (int d = 0; d < D; ++d) s += W1[kk * D + d] * mw[n * D + d];
        M[n][kk] = s;
    } else if (t < NH * DIN + NH) {
        int n = t - NH * DIN;
        float s = mb[n];
        for (int d = 0; d < D; ++d) s += b1[d] * mw[n * D + d];
        C[n] = s;
    }
    __syncthreads();

    int blk = blockIdx.x;        // b*N + j
    int b = blk >> 8;            // / N
    int j = blk & (N - 1);
    int i = t;
    const float4 f = *(const float4*)(feature + (((size_t)(b * N + i)) * N + j) * DIN);
    const float4 r4 = *(const float4*)(rs + (size_t)(b * N + i) * NH);
    float wbar = 0.f;
    {
        float rsv[NH] = {r4.x, r4.y, r4.z, r4.w};
#pragma unroll
        for (int n = 0; n < NH; ++n) {
            float s = C[n] + f.x * M[n][0] + f.y * M[n][1] + f.z * M[n][2] + f.w * M[n][3];
            s = (s >= 0.f) ? s : SLOPE * s;
            wbar += __expf(s) / rsv[n];
        }
    }
    wbar *= (1.0f / NH);
    float acc[5] = {wbar * f.x, wbar * f.y, wbar * f.z, wbar * f.w, wbar};

    int lane = t & 63, wv = t >> 6;
#pragma unroll
    for (int n = 0; n < 5; ++n) {
        float v = acc[n];
        for (int off = 32; off > 0; off >>= 1) v += __shfl_down(v, off);
        if (lane == 0) part[wv][n] = v;
    }
    __syncthreads();
    if (t < 5) gacc[t] = part[0][t] + part[1][t] + part[2][t] + part[3][t];
    __syncthreads();
    if (t < D) {
        float hv = gacc[4] * b1[t];
#pragma unroll
        for (int kk = 0; kk < DIN; ++kk) hv += gacc[kk] * W1[kk * D + t];
        h[(size_t)blk * D + t] = hv;
    }
}

// ---------------------------------------------------------------------------
// BatchNorm stats over (B,N) per channel. grid = D, block = 256.
// ---------------------------------------------------------------------------
__global__ void k_bnstats(const float* __restrict__ h,
                          float* __restrict__ mean, float* __restrict__ inv) {
    __shared__ float ps[4], pq[4];
    int d = blockIdx.x, t = threadIdx.x;
    float s = 0.f, sq = 0.f;
    for (int r = t; r < B * N; r += 256) {
        float v = h[(size_t)r * D + d];
        s += v;
        sq += v * v;
    }
    int lane = t & 63, wv = t >> 6;
    for (int off = 32; off > 0; off >>= 1) {
        s += __shfl_down(s, off);
        sq += __shfl_down(sq, off);
    }
    if (lane == 0) { ps[wv] = s; pq[wv] = sq; }
    __syncthreads();
    if (t == 0) {
        float S = ps[0] + ps[1] + ps[2] + ps[3];
        float Q = pq[0] + pq[1] + pq[2] + pq[3];
        float m = S * (1.0f / (B * N));
        float var = Q * (1.0f / (B * N)) - m * m;
        mean[d] = m;
        inv[d] = rsqrtf(var + EPS);
    }
}

// elementwise BN apply: x = gamma*(h-mean)*inv + beta. 65536 elements.
__global__ void k_bnapply(const float* __restrict__ h,
                          const float* __restrict__ mean, const float* __restrict__ inv,
                          const float* __restrict__ g, const float* __restrict__ be,
                          float* __restrict__ x) {
    int idx = blockIdx.x * 256 + threadIdx.x;
    int d = idx & (D - 1);
    x[idx] = g[d] * (h[idx] - mean[d]) * inv[d] + be[d];
}

// ---------------------------------------------------------------------------
// QKV projection. grid = B*N/4 (4 tokens/block), block = 256 (4 rows x 64 cols).
// Outputs laid out [b][head][n][dh] for attention locality.
// ---------------------------------------------------------------------------
__global__ void k_qkv(const float* __restrict__ x,
                      const float* __restrict__ Wq, const float* __restrict__ bq,
                      const float* __restrict__ Wk, const float* __restrict__ bk,
                      const float* __restrict__ Wv, const float* __restrict__ bv,
                      float* __restrict__ q, float* __restrict__ k, float* __restrict__ v) {
    __shared__ float xs[4][D];
    int t = threadIdx.x;
    int row0 = blockIdx.x * 4;
    xs[t >> 6][t & 63] = x[(size_t)row0 * D + t];
    __syncthreads();
    int r = t >> 6, cc = t & 63;
    int token = row0 + r;
    int b = token >> 8;          // / N
    int n = token & (N - 1);
    int head = cc >> 4, dh = cc & (DH - 1);
    size_t oidx = (((size_t)(b * NH + head)) * N + n) * DH + dh;
    float aq = bq[cc], ak = bk[cc], av = bv[cc];
#pragma unroll 8
    for (int kk = 0; kk < D; ++kk) {
        float xv = xs[r][kk];
        aq += xv * Wq[kk * D + cc];
        ak += xv * Wk[kk * D + cc];
        av += xv * Wv[kk * D + cc];
    }
    q[oidx] = aq; k[oidx] = ak; v[oidx] = av;
}

// ---------------------------------------------------------------------------
// Attention, key-parallel exact softmax.
// grid = (B*NH, N/4), block = 256 (4 waves; one wave per query, lane owns 4 keys).
// K/V rows live in registers (loads are L2-hot across blocks); wave xor-shuffle
// reductions for max / sum / o[16]. No LDS, no serial 256-chain.
// att output layout: [b][n][head*DH+dh] (token-major, D contiguous).
// ---------------------------------------------------------------------------
__global__ void k_attn(const float* __restrict__ q, const float* __restrict__ k,
                       const float* __restrict__ v, float* __restrict__ att) {
    int t = threadIdx.x;
    int lane = t & 63, w = t >> 6;
    int bh = blockIdx.x;             // b*NH + head
    int qi = blockIdx.y * 4 + w;

    const float* qbase = q + ((size_t)bh * N + qi) * DH;
    float qr[DH];
#pragma unroll
    for (int d = 0; d < DH; ++d) qr[d] = qbase[d] * 0.25f;  // 1/sqrt(16)

    const float* kb = k + (size_t)bh * N * DH;
    const float* vb = v + (size_t)bh * N * DH;

    // scores for this lane's 4 keys (immediate-consume K to limit VGPRs)
    float s[4];
#pragma unroll
    for (int j = 0; j < 4; ++j) {
        int key = lane + 64 * j;
        float acc = 0.f;
#pragma unroll
        for (int c = 0; c < 4; ++c) {
            float4 kr = *(const float4*)(kb + (size_t)key * DH + 4 * c);
            acc += qr[4*c+0]*kr.x + qr[4*c+1]*kr.y + qr[4*c+2]*kr.z + qr[4*c+3]*kr.w;
        }
        s[j] = acc;
    }
    // issue V loads now so latency overlaps the shuffle reductions
    float4 vr[4][4];
#pragma unroll
    for (int j = 0; j < 4; ++j) {
        int key = lane + 64 * j;
#pragma unroll
        for (int c = 0; c < 4; ++c)
            vr[j][c] = *(const float4*)(vb + (size_t)key * DH + 4 * c);
    }

    float m = fmaxf(fmaxf(s[0], s[1]), fmaxf(s[2], s[3]));
#pragma unroll
    for (int off = 32; off > 0; off >>= 1) m = fmaxf(m, __shfl_xor(m, off));
    float p[4], l = 0.f;
#pragma unroll
    for (int j = 0; j < 4; ++j) { p[j] = __expf(s[j] - m); l += p[j]; }
#pragma unroll
    for (int off = 32; off > 0; off >>= 1) l += __shfl_xor(l, off);

    float o[DH];
#pragma unroll
    for (int d = 0; d < DH; ++d) o[d] = 0.f;
#pragma unroll
    for (int j = 0; j < 4; ++j) {
#pragma unroll
        for (int c = 0; c < 4; ++c) {
            o[4*c+0] += p[j] * vr[j][c].x;
            o[4*c+1] += p[j] * vr[j][c].y;
            o[4*c+2] += p[j] * vr[j][c].z;
            o[4*c+3] += p[j] * vr[j][c].w;
        }
    }
#pragma unroll
    for (int d = 0; d < DH; ++d) {
#pragma unroll
        for (int off = 32; off > 0; off >>= 1) o[d] += __shfl_xor(o[d], off);
    }

    if (lane == 0) {
        float rl = 1.f / l;
        int b = bh >> 2, head = bh & (NH - 1);
        float* ob = att + ((size_t)(b * N + qi)) * D + head * DH;
#pragma unroll
        for (int c = 0; c < 4; ++c) {
            float4 val;
            val.x = o[4*c+0] * rl; val.y = o[4*c+1] * rl;
            val.z = o[4*c+2] * rl; val.w = o[4*c+3] * rl;
            *(float4*)(ob + 4 * c) = val;
        }
    }
}

// ---------------------------------------------------------------------------
// O-projection + residual + LayerNorm. grid = B*N (one token/block), block = 64.
// ---------------------------------------------------------------------------
__global__ void k_oproj_ln(const float* __restrict__ att, const float* __restrict__ Wo,
                           const float* __restrict__ bo, const float* __restrict__ lg,
                           const float* __restrict__ lb, float* __restrict__ x) {
    __shared__ float as[D];
    int t = threadIdx.x;
    int token = blockIdx.x;
    as[t] = att[(size_t)token * D + t];
    __syncthreads();
    float o = bo[t];
#pragma unroll 8
    for (int kk = 0; kk < D; ++kk) o += as[kk] * Wo[kk * D + t];
    float r = x[(size_t)token * D + t] + o;
    float s = r, sq = r * r;
    for (int off = 32; off > 0; off >>= 1) {
        s += __shfl_xor(s, off);
        sq += __shfl_xor(sq, off);
    }
    float mean = s * (1.0f / D);
    float var = sq * (1.0f / D) - mean * mean;
    float inv = rsqrtf(var + EPS);
    x[(size_t)token * D + t] = lg[t] * (r - mean) * inv + lb[t];
}

// ---------------------------------------------------------------------------
// FFN (64 -> 128 relu -> 64) + residual + LayerNorm. grid = B*N, block = 128.
// ---------------------------------------------------------------------------
__global__ void k_ffn_ln(const float* __restrict__ Wff1, const float* __restrict__ bff1,
                         const float* __restrict__ Wff2, const float* __restrict__ bff2,
                         const float* __restrict__ lg, const float* __restrict__ lb,
                         float* __restrict__ x) {
    __shared__ float xr[D];
    __shared__ float f1[2 * D];
    int t = threadIdx.x;
    int token = blockIdx.x;
    if (t < D) xr[t] = x[(size_t)token * D + t];
    __syncthreads();
    float a = bff1[t];
#pragma unroll 8
    for (int kk = 0; kk < D; ++kk) a += xr[kk] * Wff1[kk * 2 * D + t];
    f1[t] = fmaxf(a, 0.f);
    __syncthreads();
    if (t < D) {
        float o = bff2[t];
#pragma unroll 8
        for (int kk = 0; kk < 2 * D; ++kk) o += f1[kk] * Wff2[kk * D + t];
        float r = xr[t] + o;
        float s = r, sq = r * r;
        for (int off = 32; off > 0; off >>= 1) {
            s += __shfl_xor(s, off);
            sq += __shfl_xor(sq, off);
        }
        float mean = s * (1.0f / D);
        float var = sq * (1.0f / D) - mean * mean;
        float inv = rsqrtf(var + EPS);
        x[(size_t)token * D + t] = lg[t] * (r - mean) * inv + lb[t];
    }
}

extern "C" void kernel_launch(void* const* d_in, const int* in_sizes, int n_in,
                              void* d_out, int out_size, void* d_ws, size_t ws_size,
                              hipStream_t stream) {
    const float* feature = (const float*)d_in[0];
    const float* W1   = (const float*)d_in[1];
    const float* b1   = (const float*)d_in[2];
    const float* mw   = (const float*)d_in[3];
    const float* mb   = (const float*)d_in[4];
    const float* bn_g = (const float*)d_in[5];
    const float* bn_b = (const float*)d_in[6];
    const float* Wq   = (const float*)d_in[7];
    const float* bq   = (const float*)d_in[8];
    const float* Wk   = (const float*)d_in[9];
    const float* bk   = (const float*)d_in[10];
    const float* Wv   = (const float*)d_in[11];
    const float* bv   = (const float*)d_in[12];
    const float* Wo   = (const float*)d_in[13];
    const float* bo   = (const float*)d_in[14];
    const float* ln1g = (const float*)d_in[15];
    const float* ln1b = (const float*)d_in[16];
    const float* Wff1 = (const float*)d_in[17];
    const float* bff1 = (const float*)d_in[18];
    const float* Wff2 = (const float*)d_in[19];
    const float* bff2 = (const float*)d_in[20];
    const float* ln2g = (const float*)d_in[21];
    const float* ln2b = (const float*)d_in[22];

    float* ws   = (float*)d_ws;
    float* rs   = ws;                    // B*N*NH          = 4096
    float* h    = rs + B * N * NH;       // B*N*D           = 65536
    float* mean = h + B * N * D;         // D
    float* inv  = mean + D;              // D
    float* q    = inv + D;               // B*N*D
    float* k    = q + B * N * D;         // B*N*D
    float* v    = k + B * N * D;         // B*N*D
    float* att  = v + B * N * D;         // B*N*D
    float* x    = (float*)d_out;         // running (B,N,D) activation

    k_rowsum<<<B * N, 256, 0, stream>>>(feature, W1, b1, mw, mb, rs);
    k_aggregate<<<B * N, 256, 0, stream>>>(feature, W1, b1, mw, mb, rs, h);
    k_bnstats<<<D, 256, 0, stream>>>(h, mean, inv);
    k_bnapply<<<(B * N * D) / 256, 256, 0, stream>>>(h, mean, inv, bn_g, bn_b, x);

    for (int l = 0; l < NL; ++l) {
        k_qkv<<<(B * N) / 4, 256, 0, stream>>>(x,
            Wq + (size_t)l * D * D, bq + (size_t)l * D,
            Wk + (size_t)l * D * D, bk + (size_t)l * D,
            Wv + (size_t)l * D * D, bv + (size_t)l * D, q, k, v);
        dim3 g2(B * NH, N / 4);
        k_attn<<<g2, 256, 0, stream>>>(q, k, v, att);
        k_oproj_ln<<<B * N, 64, 0, stream>>>(att,
            Wo + (size_t)l * D * D, bo + (size_t)l * D,
            ln1g + (size_t)l * D, ln1b + (size_t)l * D, x);
        k_ffn_ln<<<B * N, 128, 0, stream>>>(
            Wff1 + (size_t)l * 2 * D * D, bff1 + (size_t)l * 2 * D,
            Wff2 + (size_t)l * 2 * D * D, bff2 + (size_t)l * D,
            ln2g + (size_t)l * D, ln2b + (size_t)l * D, x);
    }
}

// Round 3
// 167.281 us; speedup vs baseline: 1.3975x; 1.0389x over previous
//
#include <hip/hip_runtime.h>
#include <hip/hip_bf16.h>
#include <math.h>

#define B 4
#define N 256
#define DIN 4
#define D 64
#define NH 4
#define NL 2
#define DH 16

constexpr float EPS = 1e-5f;
constexpr float SLOPE = 0.01f;

// ---------------------------------------------------------------------------
// Phase B: rowsum[n, b, i] = sum_j exp(leaky(feature[b,i,j,:]·M[n] + c[n]))
// where M[n][k] = sum_d W1[k][d]*mw[n][d], c[n] = b1·mw[n] + mb[n].
// grid = B*N (one block per (b,i)), block = 256 (one thread per j)
// ---------------------------------------------------------------------------
__global__ void k_rowsum(const float* __restrict__ feature,
                         const float* __restrict__ W1,
                         const float* __restrict__ b1,
                         const float* __restrict__ mw,
                         const float* __restrict__ mb,
                         float* __restrict__ rs) {
    __shared__ float M[NH][DIN];
    __shared__ float C[NH];
    __shared__ float part[4][NH];
    int t = threadIdx.x;
    if (t < NH * DIN) {
        int n = t / DIN, kk = t % DIN;
        float s = 0.f;
        for (int d = 0; d < D; ++d) s += W1[kk * D + d] * mw[n * D + d];
        M[n][kk] = s;
    } else if (t < NH * DIN + NH) {
        int n = t - NH * DIN;
        float s = mb[n];
        for (int d = 0; d < D; ++d) s += b1[d] * mw[n * D + d];
        C[n] = s;
    }
    __syncthreads();

    int bi = blockIdx.x;  // b*N + i
    const float4 f = *(const float4*)(feature + ((size_t)bi * N + t) * DIN);
    float e[NH];
#pragma unroll
    for (int n = 0; n < NH; ++n) {
        float s = C[n] + f.x * M[n][0] + f.y * M[n][1] + f.z * M[n][2] + f.w * M[n][3];
        s = (s >= 0.f) ? s : SLOPE * s;
        e[n] = __expf(s);
    }
    int lane = t & 63, wv = t >> 6;
#pragma unroll
    for (int n = 0; n < NH; ++n) {
        float v = e[n];
        for (int off = 32; off > 0; off >>= 1) v += __shfl_down(v, off);
        if (lane == 0) part[wv][n] = v;
    }
    __syncthreads();
    if (t < NH) rs[bi * NH + t] = part[0][t] + part[1][t] + part[2][t] + part[3][t];
}

// ---------------------------------------------------------------------------
// Phase C: g[b,j,0:4] = sum_i wbar * feature[b,i,j,:], S = sum_i wbar,
// then h[b,j,:] = g·W1 + S*b1.  grid = B*N (one block per (b,j)), block = 256.
// ---------------------------------------------------------------------------
__global__ void k_aggregate(const float* __restrict__ feature,
                            const float* __restrict__ W1,
                            const float* __restrict__ b1,
                            const float* __restrict__ mw,
                            const float* __restrict__ mb,
                            const float* __restrict__ rs,
                            float* __restrict__ h) {
    __shared__ float M[NH][DIN];
    __shared__ float C[NH];
    __shared__ float part[4][5];
    __shared__ float gacc[5];
    int t = threadIdx.x;
    if (t < NH * DIN) {
        int n = t / DIN, kk = t % DIN;
        float s = 0.f;
        for (int d = 0; d < D; ++d) s += W1[kk * D + d] * mw[n * D + d];
        M[n][kk] = s;
    } else if (t < NH * DIN + NH) {
        int n = t - NH * DIN;
        float s = mb[n];
        for (int d = 0; d < D; ++d) s += b1[d] * mw[n * D + d];
        C[n] = s;
    }
    __syncthreads();

    int blk = blockIdx.x;        // b*N + j
    int b = blk >> 8;            // / N
    int j = blk & (N - 1);
    int i = t;
    const float4 f = *(const float4*)(feature + (((size_t)(b * N + i)) * N + j) * DIN);
    const float4 r4 = *(const float4*)(rs + (size_t)(b * N + i) * NH);
    float wbar = 0.f;
    {
        float rsv[NH] = {r4.x, r4.y, r4.z, r4.w};
#pragma unroll
        for (int n = 0; n < NH; ++n) {
            float s = C[n] + f.x * M[n][0] + f.y * M[n][1] + f.z * M[n][2] + f.w * M[n][3];
            s = (s >= 0.f) ? s : SLOPE * s;
            wbar += __expf(s) / rsv[n];
        }
    }
    wbar *= (1.0f / NH);
    float acc[5] = {wbar * f.x, wbar * f.y, wbar * f.z, wbar * f.w, wbar};

    int lane = t & 63, wv = t >> 6;
#pragma unroll
    for (int n = 0; n < 5; ++n) {
        float v = acc[n];
        for (int off = 32; off > 0; off >>= 1) v += __shfl_down(v, off);
        if (lane == 0) part[wv][n] = v;
    }
    __syncthreads();
    if (t < 5) gacc[t] = part[0][t] + part[1][t] + part[2][t] + part[3][t];
    __syncthreads();
    if (t < D) {
        float hv = gacc[4] * b1[t];
#pragma unroll
        for (int kk = 0; kk < DIN; ++kk) hv += gacc[kk] * W1[kk * D + t];
        h[(size_t)blk * D + t] = hv;
    }
}

// ---------------------------------------------------------------------------
// BatchNorm stats over (B,N) per channel. grid = D, block = 256.
// ---------------------------------------------------------------------------
__global__ void k_bnstats(const float* __restrict__ h,
                          float* __restrict__ mean, float* __restrict__ inv) {
    __shared__ float ps[4], pq[4];
    int d = blockIdx.x, t = threadIdx.x;
    float s = 0.f, sq = 0.f;
    for (int r = t; r < B * N; r += 256) {
        float v = h[(size_t)r * D + d];
        s += v;
        sq += v * v;
    }
    int lane = t & 63, wv = t >> 6;
    for (int off = 32; off > 0; off >>= 1) {
        s += __shfl_down(s, off);
        sq += __shfl_down(sq, off);
    }
    if (lane == 0) { ps[wv] = s; pq[wv] = sq; }
    __syncthreads();
    if (t == 0) {
        float S = ps[0] + ps[1] + ps[2] + ps[3];
        float Q = pq[0] + pq[1] + pq[2] + pq[3];
        float m = S * (1.0f / (B * N));
        float var = Q * (1.0f / (B * N)) - m * m;
        mean[d] = m;
        inv[d] = rsqrtf(var + EPS);
    }
}

// elementwise BN apply: x = gamma*(h-mean)*inv + beta. 65536 elements.
__global__ void k_bnapply(const float* __restrict__ h,
                          const float* __restrict__ mean, const float* __restrict__ inv,
                          const float* __restrict__ g, const float* __restrict__ be,
                          float* __restrict__ x) {
    int idx = blockIdx.x * 256 + threadIdx.x;
    int d = idx & (D - 1);
    x[idx] = g[d] * (h[idx] - mean[d]) * inv[d] + be[d];
}

// ---------------------------------------------------------------------------
// QKV projection. grid = B*N/4 (4 tokens/block), block = 256 (4 rows x 64 cols).
// Outputs laid out [b][head][n][dh] for attention locality.
// ---------------------------------------------------------------------------
__global__ void k_qkv(const float* __restrict__ x,
                      const float* __restrict__ Wq, const float* __restrict__ bq,
                      const float* __restrict__ Wk, const float* __restrict__ bk,
                      const float* __restrict__ Wv, const float* __restrict__ bv,
                      float* __restrict__ q, float* __restrict__ k, float* __restrict__ v) {
    __shared__ float xs[4][D];
    int t = threadIdx.x;
    int row0 = blockIdx.x * 4;
    xs[t >> 6][t & 63] = x[(size_t)row0 * D + t];
    __syncthreads();
    int r = t >> 6, cc = t & 63;
    int token = row0 + r;
    int b = token >> 8;          // / N
    int n = token & (N - 1);
    int head = cc >> 4, dh = cc & (DH - 1);
    size_t oidx = (((size_t)(b * NH + head)) * N + n) * DH + dh;
    float aq = bq[cc], ak = bk[cc], av = bv[cc];
#pragma unroll 8
    for (int kk = 0; kk < D; ++kk) {
        float xv = xs[r][kk];
        aq += xv * Wq[kk * D + cc];
        ak += xv * Wk[kk * D + cc];
        av += xv * Wv[kk * D + cc];
    }
    q[oidx] = aq; k[oidx] = ak; v[oidx] = av;
}

// ---------------------------------------------------------------------------
// Fused transformer layer tail: attention + O-proj + LN1 + FFN + LN2.
// grid = (B, N/4) = 256 blocks, block = 256 (4 waves).
// Attention phase: wave w = head w; lane owns keys {lane+64j}; K/V in regs
// (loaded once), 4 queries processed with wave shuffle reductions; att scores
// land in LDS (never global). Post phase: wave w = token q0+w, lane = channel;
// oproj/LN1/FFN/LN2 all per-token in LDS/regs.
// ---------------------------------------------------------------------------
__global__ void __launch_bounds__(256, 2) k_layer(
    const float* __restrict__ q, const float* __restrict__ k,
    const float* __restrict__ v,
    const float* __restrict__ Wo, const float* __restrict__ bo,
    const float* __restrict__ ln1g, const float* __restrict__ ln1b,
    const float* __restrict__ Wff1, const float* __restrict__ bff1,
    const float* __restrict__ Wff2, const float* __restrict__ bff2,
    const float* __restrict__ ln2g, const float* __restrict__ ln2b,
    float* __restrict__ x) {
    __shared__ float attS[4][D];
    __shared__ float xs1[4][D];
    __shared__ float f1s[4][2 * D];
    int t = threadIdx.x;
    int lane = t & 63, w = t >> 6;
    int b = blockIdx.x;
    int q0 = blockIdx.y * 4;
    int bh = b * NH + w;     // wave = head in attention phase

    const float* kb = k + (size_t)bh * N * DH;
    const float* vb = v + (size_t)bh * N * DH;
    float4 Kr[4][4], Vr[4][4];
#pragma unroll
    for (int j = 0; j < 4; ++j) {
        int key = lane + 64 * j;
#pragma unroll
        for (int c = 0; c < 4; ++c) {
            Kr[j][c] = *(const float4*)(kb + (size_t)key * DH + 4 * c);
            Vr[j][c] = *(const float4*)(vb + (size_t)key * DH + 4 * c);
        }
    }
#pragma unroll
    for (int qq = 0; qq < 4; ++qq) {
        const float* qp = q + ((size_t)bh * N + q0 + qq) * DH;  // wave-uniform
        float sq[DH];
#pragma unroll
        for (int d = 0; d < DH; ++d) sq[d] = qp[d] * 0.25f;  // 1/sqrt(16)
        float s[4];
#pragma unroll
        for (int j = 0; j < 4; ++j) {
            float a = 0.f;
#pragma unroll
            for (int c = 0; c < 4; ++c)
                a += sq[4*c+0]*Kr[j][c].x + sq[4*c+1]*Kr[j][c].y +
                     sq[4*c+2]*Kr[j][c].z + sq[4*c+3]*Kr[j][c].w;
            s[j] = a;
        }
        float m = fmaxf(fmaxf(s[0], s[1]), fmaxf(s[2], s[3]));
#pragma unroll
        for (int off = 32; off > 0; off >>= 1) m = fmaxf(m, __shfl_xor(m, off));
        float p[4], l = 0.f;
#pragma unroll
        for (int j = 0; j < 4; ++j) { p[j] = __expf(s[j] - m); l += p[j]; }
#pragma unroll
        for (int off = 32; off > 0; off >>= 1) l += __shfl_xor(l, off);
        float o[DH];
#pragma unroll
        for (int d = 0; d < DH; ++d) o[d] = 0.f;
#pragma unroll
        for (int j = 0; j < 4; ++j) {
#pragma unroll
            for (int c = 0; c < 4; ++c) {
                o[4*c+0] += p[j] * Vr[j][c].x;
                o[4*c+1] += p[j] * Vr[j][c].y;
                o[4*c+2] += p[j] * Vr[j][c].z;
                o[4*c+3] += p[j] * Vr[j][c].w;
            }
        }
#pragma unroll
        for (int d = 0; d < DH; ++d) {
#pragma unroll
            for (int off = 32; off > 0; off >>= 1) o[d] += __shfl_xor(o[d], off);
        }
        if (lane == 0) {
            float rl = 1.f / l;
#pragma unroll
            for (int d = 0; d < DH; ++d) attS[qq][w * DH + d] = o[d] * rl;
        }
    }
    __syncthreads();

    // ----- post phase: wave w = token q0+w, lane = channel -----
    int token = q0 + w;
    int ch = lane;
    size_t xidx = ((size_t)b * N + token) * D + ch;
    float oo = bo[ch];
#pragma unroll 8
    for (int kk = 0; kk < D; ++kk) oo += attS[w][kk] * Wo[kk * D + ch];
    float r = x[xidx] + oo;
    float s1 = r, sq1 = r * r;
#pragma unroll
    for (int off = 32; off > 0; off >>= 1) {
        s1 += __shfl_xor(s1, off);
        sq1 += __shfl_xor(sq1, off);
    }
    float mean1 = s1 * (1.0f / D);
    float var1 = sq1 * (1.0f / D) - mean1 * mean1;
    float x1 = ln1g[ch] * (r - mean1) * rsqrtf(var1 + EPS) + ln1b[ch];
    xs1[w][ch] = x1;
    __syncthreads();

    float a0 = bff1[ch], a1 = bff1[ch + 64];
#pragma unroll 8
    for (int kk = 0; kk < D; ++kk) {
        float xv = xs1[w][kk];
        a0 += xv * Wff1[kk * 2 * D + ch];
        a1 += xv * Wff1[kk * 2 * D + ch + 64];
    }
    f1s[w][ch] = fmaxf(a0, 0.f);
    f1s[w][ch + 64] = fmaxf(a1, 0.f);
    __syncthreads();

    float o2 = bff2[ch];
#pragma unroll 8
    for (int kk = 0; kk < 2 * D; ++kk) o2 += f1s[w][kk] * Wff2[kk * D + ch];
    float r2 = x1 + o2;
    float s2 = r2, sq2 = r2 * r2;
#pragma unroll
    for (int off = 32; off > 0; off >>= 1) {
        s2 += __shfl_xor(s2, off);
        sq2 += __shfl_xor(sq2, off);
    }
    float mean2 = s2 * (1.0f / D);
    float var2 = sq2 * (1.0f / D) - mean2 * mean2;
    x[xidx] = ln2g[ch] * (r2 - mean2) * rsqrtf(var2 + EPS) + ln2b[ch];
}

extern "C" void kernel_launch(void* const* d_in, const int* in_sizes, int n_in,
                              void* d_out, int out_size, void* d_ws, size_t ws_size,
                              hipStream_t stream) {
    const float* feature = (const float*)d_in[0];
    const float* W1   = (const float*)d_in[1];
    const float* b1   = (const float*)d_in[2];
    const float* mw   = (const float*)d_in[3];
    const float* mb   = (const float*)d_in[4];
    const float* bn_g = (const float*)d_in[5];
    const float* bn_b = (const float*)d_in[6];
    const float* Wq   = (const float*)d_in[7];
    const float* bq   = (const float*)d_in[8];
    const float* Wk   = (const float*)d_in[9];
    const float* bk   = (const float*)d_in[10];
    const float* Wv   = (const float*)d_in[11];
    const float* bv   = (const float*)d_in[12];
    const float* Wo   = (const float*)d_in[13];
    const float* bo   = (const float*)d_in[14];
    const float* ln1g = (const float*)d_in[15];
    const float* ln1b = (const float*)d_in[16];
    const float* Wff1 = (const float*)d_in[17];
    const float* bff1 = (const float*)d_in[18];
    const float* Wff2 = (const float*)d_in[19];
    const float* bff2 = (const float*)d_in[20];
    const float* ln2g = (const float*)d_in[21];
    const float* ln2b = (const float*)d_in[22];

    float* ws   = (float*)d_ws;
    float* rs   = ws;                    // B*N*NH          = 4096
    float* h    = rs + B * N * NH;       // B*N*D           = 65536
    float* mean = h + B * N * D;         // D
    float* inv  = mean + D;              // D
    float* q    = inv + D;               // B*N*D
    float* k    = q + B * N * D;         // B*N*D
    float* v    = k + B * N * D;         // B*N*D
    float* x    = (float*)d_out;         // running (B,N,D) activation

    k_rowsum<<<B * N, 256, 0, stream>>>(feature, W1, b1, mw, mb, rs);
    k_aggregate<<<B * N, 256, 0, stream>>>(feature, W1, b1, mw, mb, rs, h);
    k_bnstats<<<D, 256, 0, stream>>>(h, mean, inv);
    k_bnapply<<<(B * N * D) / 256, 256, 0, stream>>>(h, mean, inv, bn_g, bn_b, x);

    for (int l = 0; l < NL; ++l) {
        k_qkv<<<(B * N) / 4, 256, 0, stream>>>(x,
            Wq + (size_t)l * D * D, bq + (size_t)l * D,
            Wk + (size_t)l * D * D, bk + (size_t)l * D,
            Wv + (size_t)l * D * D, bv + (size_t)l * D, q, k, v);
        dim3 g2(B, N / 4);
        k_layer<<<g2, 256, 0, stream>>>(q, k, v,
            Wo + (size_t)l * D * D, bo + (size_t)l * D,
            ln1g + (size_t)l * D, ln1b + (size_t)l * D,
            Wff1 + (size_t)l * 2 * D * D, bff1 + (size_t)l * 2 * D,
            Wff2 + (size_t)l * 2 * D * D, bff2 + (size_t)l * D,
            ln2g + (size_t)l * D, ln2b + (size_t)l * D, x);
    }
}